// Round 8
// baseline (142.455 us; speedup 1.0000x reference)
//
#include <hip/hip_runtime.h>
#include <cstdint>
#include <cstddef>

typedef short bf16x8 __attribute__((ext_vector_type(8)));
typedef float f32x4 __attribute__((ext_vector_type(4)));
typedef float f32x2 __attribute__((ext_vector_type(2)));

__device__ __forceinline__ unsigned short f2bf(float f) {
    union { float f; uint32_t u; } v; v.f = f;
    uint32_t r = v.u + 0x7FFFu + ((v.u >> 16) & 1u);   // round-to-nearest-even
    return (unsigned short)(r >> 16);
}

__device__ __forceinline__ float bf2f(unsigned short u) {
    union { uint32_t u; float f; } v; v.u = (uint32_t)u << 16;
    return v.f;
}

// ---------------- prep: cast X to bf16  +  transpose-cast B ----------------

__global__ void prep_kernel(const float* __restrict__ X,
                            unsigned short* __restrict__ Xbf, int n4,
                            const float* __restrict__ B,
                            unsigned short* __restrict__ Bt, int H,
                            int castBlocks) {
    if ((int)blockIdx.x < castBlocks) {
        int i = blockIdx.x * 256 + threadIdx.x;
        if (i < n4) {
            float4 v = ((const float4*)X)[i];
            ushort4 o;
            o.x = f2bf(v.x); o.y = f2bf(v.y); o.z = f2bf(v.z); o.w = f2bf(v.w);
            ((ushort4*)Xbf)[i] = o;
        }
        return;
    }
    __shared__ float tile[32][33];
    int tb = blockIdx.x - castBlocks;
    int tilesPerRow = H / 32;
    int bx = (tb % tilesPerRow) * 32;   // n tile
    int by = (tb / tilesPerRow) * 32;   // k tile
    int tx = threadIdx.x & 31, ty = threadIdx.x >> 5;   // (32,8)
#pragma unroll
    for (int i = 0; i < 32; i += 8)
        tile[ty + i][tx] = B[(size_t)(by + ty + i) * H + bx + tx];
    __syncthreads();
#pragma unroll
    for (int i = 0; i < 32; i += 8)
        Bt[(size_t)(bx + ty + i) * H + by + tx] = f2bf(tile[tx][ty + i]);
}

// ---------------- fast GEMM: S = A * Bt^T, split-K=2, bf16 out --------------
// Block tile 256x128, BK=64, 4 waves, wave tile 128x64 (8x4 grid of 16x16x32
// MFMA). Single 48KB LDS buffer, XOR-swizzled layout (verified 0 conflicts),
// global_load_lds width=16 staging. kt=0 -> S0, kt=1 -> S1 (immutable
// afterwards -> race-free scan). XCD swizzle for L2 A-reuse.
// At 880 TF this sits on the documented m97-structure plateau — left as-is.

__global__ __launch_bounds__(256, 2) void gemm_sk_bf16out(
    const unsigned short* __restrict__ A,
    const unsigned short* __restrict__ Bt,
    unsigned short* __restrict__ S0, unsigned short* __restrict__ S1,
    int M, int N, int K, int gridM, int gridN)
{
    __shared__ __attribute__((aligned(16))) unsigned short sA[256 * 64]; // 32KB
    __shared__ __attribute__((aligned(16))) unsigned short sB[128 * 64]; // 16KB

    const int tid  = threadIdx.x;
    const int wave = tid >> 6;
    const int lane = tid & 63;

    int b = blockIdx.x;
    int mt, nt, kt;
    if ((gridM & 7) == 0) {
        int x = b & 7, g = b >> 3;
        int mPerX = gridM >> 3;
        int ml = g % mPerX, g2 = g / mPerX;
        nt = g2 % gridN;
        kt = g2 / gridN;
        mt = x * mPerX + ml;
    } else {
        mt = b % gridM;
        nt = (b / gridM) % gridN;
        kt = b / (gridM * gridN);
    }
    const int m0 = mt * 256;
    const int n0 = nt * 128;
    const int ksize = K / 2;
    const int kbase = kt * ksize;

    const int srow = lane >> 3;
    const int scol = ((lane & 7) ^ srow) * 8;

    const int quad = lane >> 4;
    const int l16  = lane & 15;
    const int wm = wave >> 1;
    const int wn = wave & 1;
    const int s7 = l16 & 7;
    const int c0 = (quad ^ s7) * 16;
    const int c1 = ((quad + 4) ^ s7) * 16;

    f32x4 acc[8][4];
#pragma unroll
    for (int i = 0; i < 8; ++i)
#pragma unroll
        for (int j = 0; j < 4; ++j)
            acc[i][j] = (f32x4){0.f, 0.f, 0.f, 0.f};

    const unsigned short* Ab = A  + (size_t)m0 * K;
    const unsigned short* Bb = Bt + (size_t)n0 * K;

    const int rA = (wm * 16 + (l16 >> 3)) * 1024 + s7 * 128;
    const int rB = (wn * 8  + (l16 >> 3)) * 1024 + s7 * 128;

    for (int k0 = kbase; k0 < kbase + ksize; k0 += 64) {
#pragma unroll
        for (int i = 0; i < 8; ++i) {
            const int t = wave * 8 + i;
            const unsigned short* ga = Ab + (size_t)(t * 8 + srow) * K + (k0 + scol);
            __builtin_amdgcn_global_load_lds(
                (const __attribute__((address_space(1))) void*)ga,
                (__attribute__((address_space(3))) void*)(sA + t * 512),
                16, 0, 0);
        }
#pragma unroll
        for (int i = 0; i < 4; ++i) {
            const int t = wave * 4 + i;
            const unsigned short* gb = Bb + (size_t)(t * 8 + srow) * K + (k0 + scol);
            __builtin_amdgcn_global_load_lds(
                (const __attribute__((address_space(1))) void*)gb,
                (__attribute__((address_space(3))) void*)(sB + t * 512),
                16, 0, 0);
        }
        __syncthreads();

#pragma unroll
        for (int kk = 0; kk < 2; ++kk) {
            const int co = kk ? c1 : c0;
            bf16x8 af[8], bfr[4];
#pragma unroll
            for (int im = 0; im < 8; ++im)
                af[im] = *(const bf16x8*)((const char*)sA + rA + im * 2048 + co);
#pragma unroll
            for (int in = 0; in < 4; ++in)
                bfr[in] = *(const bf16x8*)((const char*)sB + rB + in * 2048 + co);
#pragma unroll
            for (int im = 0; im < 8; ++im)
#pragma unroll
                for (int in = 0; in < 4; ++in)
                    acc[im][in] = __builtin_amdgcn_mfma_f32_16x16x32_bf16(
                        af[im], bfr[in], acc[im][in], 0, 0, 0);
        }
        __syncthreads();
    }

    unsigned short* __restrict__ S = (kt == 0) ? S0 : S1;
#pragma unroll
    for (int im = 0; im < 8; ++im) {
#pragma unroll
        for (int in = 0; in < 4; ++in) {
            int col = n0 + wn * 64 + in * 16 + l16;
#pragma unroll
            for (int r = 0; r < 4; ++r) {
                int row = m0 + wm * 128 + im * 16 + quad * 4 + r;
                S[(size_t)row * N + col] = f2bf(acc[im][in][r]);
            }
        }
    }
}

// ---------------- mid-tier GEMM (fp32 out, non-split; round-3 proven) -------

__device__ __forceinline__ void stage_tile128(
    const unsigned short* __restrict__ Ab, const unsigned short* __restrict__ Bb,
    unsigned short* sAp, unsigned short* sBp,
    int wave, int srow, int scol, int k0, int K)
{
#pragma unroll
    for (int i = 0; i < 4; ++i) {
        const int t = wave * 4 + i;
        const unsigned short* ga = Ab + (size_t)(t * 8 + srow) * K + (k0 + scol);
        __builtin_amdgcn_global_load_lds(
            (const __attribute__((address_space(1))) void*)ga,
            (__attribute__((address_space(3))) void*)(sAp + t * 512),
            16, 0, 0);
        const unsigned short* gb = Bb + (size_t)(t * 8 + srow) * K + (k0 + scol);
        __builtin_amdgcn_global_load_lds(
            (const __attribute__((address_space(1))) void*)gb,
            (__attribute__((address_space(3))) void*)(sBp + t * 512),
            16, 0, 0);
    }
}

__global__ __launch_bounds__(256, 4) void gemm_f32out(
    const unsigned short* __restrict__ A,
    const unsigned short* __restrict__ Bt,
    float* __restrict__ C, int M, int N, int K, int gridM)
{
    __shared__ __attribute__((aligned(16))) unsigned short sA[128 * 64];
    __shared__ __attribute__((aligned(16))) unsigned short sB[128 * 64];

    const int tid  = threadIdx.x;
    const int wave = tid >> 6;
    const int lane = tid & 63;

    int b = blockIdx.x;
    int mt, nt;
    if ((gridM & 7) == 0) {
        int x = b & 7, g = b >> 3;
        int mPerX = gridM >> 3;
        mt = x * mPerX + (g % mPerX);
        nt = g / mPerX;
    } else {
        mt = b % gridM;
        nt = b / gridM;
    }
    const int m0 = mt * 128;
    const int n0 = nt * 128;

    const int srow = lane >> 3;
    const int scol = ((lane & 7) ^ srow) * 8;
    const int quad = lane >> 4;
    const int l16  = lane & 15;
    const int wm = wave >> 1;
    const int wn = wave & 1;
    const int s7 = l16 & 7;
    const int rbaseA = (wm * 8 + (l16 >> 3)) * 1024 + s7 * 128;
    const int rbaseB = (wn * 8 + (l16 >> 3)) * 1024 + s7 * 128;
    const int coff0 = (quad ^ s7) * 16;
    const int coff1 = ((quad + 4) ^ s7) * 16;

    f32x4 acc[4][4];
#pragma unroll
    for (int i = 0; i < 4; ++i)
#pragma unroll
        for (int j = 0; j < 4; ++j)
            acc[i][j] = (f32x4){0.f, 0.f, 0.f, 0.f};

    const unsigned short* Ab = A  + (size_t)m0 * K;
    const unsigned short* Bb = Bt + (size_t)n0 * K;

    for (int k0 = 0; k0 < K; k0 += 64) {
        stage_tile128(Ab, Bb, sA, sB, wave, srow, scol, k0, K);
        __syncthreads();
        bf16x8 af[2][4], bfr[2][4];
#pragma unroll
        for (int t = 0; t < 4; ++t) {
            const char* pa = (const char*)sA + rbaseA + t * 2048;
            af[0][t]  = *(const bf16x8*)(pa + coff0);
            af[1][t]  = *(const bf16x8*)(pa + coff1);
            const char* pb = (const char*)sB + rbaseB + t * 2048;
            bfr[0][t] = *(const bf16x8*)(pb + coff0);
            bfr[1][t] = *(const bf16x8*)(pb + coff1);
        }
#pragma unroll
        for (int kk = 0; kk < 2; ++kk)
#pragma unroll
            for (int im = 0; im < 4; ++im)
#pragma unroll
                for (int in = 0; in < 4; ++in)
                    acc[im][in] = __builtin_amdgcn_mfma_f32_16x16x32_bf16(
                        af[kk][im], bfr[kk][in], acc[im][in], 0, 0, 0);
        __syncthreads();
    }

#pragma unroll
    for (int im = 0; im < 4; ++im)
#pragma unroll
        for (int in = 0; in < 4; ++in) {
            int col = n0 + wn * 64 + in * 16 + l16;
#pragma unroll
            for (int r = 0; r < 4; ++r) {
                int row = m0 + wm * 64 + im * 16 + quad * 4 + r;
                C[(size_t)row * N + col] = acc[im][in][r];
            }
        }
}

// ---------------- scan (fast path) ----------------
// y[t] = a*y[t-1] + (S0[t]+S1[t]).  |a| <= 2^-5 -> 4-term warm-up
// reconstructs the carry-in to a^4*|y| ~ 3e-6 (<< bf16 quantization ~2e-3).
// S0/S1 immutable -> race-free. CHUNK=16: 1024 blocks (4/CU), warm-read
// overhead 25% (was 50% at W=8). Nontemporal out-stores (out is written once,
// never re-read) keep S0/S1 warm rows resident in L2/L3.

__global__ void scan_splitk_bf16(const unsigned short* __restrict__ S0,
                                 const unsigned short* __restrict__ S1,
                                 const float* __restrict__ a_diag,
                                 float* __restrict__ out,
                                 int H2, int chunk) {
    int tid = blockIdx.x * blockDim.x + threadIdx.x;
    int hp = tid % H2, c = tid / H2;
    float2 av = ((const float2*)a_diag)[hp];
    const ushort2* S0v = (const ushort2*)S0;
    const ushort2* S1v = (const ushort2*)S1;
    f32x2* outv = (f32x2*)out;

    float y0 = 0.f, y1 = 0.f;
    if (c > 0) {
        size_t r0 = (size_t)c * chunk - 4;
#pragma unroll
        for (int i = 0; i < 4; ++i) {
            size_t idx = (r0 + i) * H2 + hp;
            ushort2 u = S0v[idx], w = S1v[idx];
            y0 = fmaf(av.x, y0, bf2f(u.x) + bf2f(w.x));
            y1 = fmaf(av.y, y1, bf2f(u.y) + bf2f(w.y));
        }
    }
    size_t idx = (size_t)c * chunk * H2 + hp;
    ushort2 u = S0v[idx], w = S1v[idx];
    for (int t = 0; t < chunk - 1; ++t) {
        size_t idx2 = idx + H2;
        ushort2 un = S0v[idx2], wn = S1v[idx2];   // prefetch next row
        y0 = fmaf(av.x, y0, bf2f(u.x) + bf2f(w.x));
        y1 = fmaf(av.y, y1, bf2f(u.y) + bf2f(w.y));
        __builtin_nontemporal_store((f32x2){y0, y1}, &outv[idx]);
        u = un; w = wn; idx = idx2;
    }
    y0 = fmaf(av.x, y0, bf2f(u.x) + bf2f(w.x));
    y1 = fmaf(av.y, y1, bf2f(u.y) + bf2f(w.y));
    __builtin_nontemporal_store((f32x2){y0, y1}, &outv[idx]);
}

// ---------------- mid-tier scan (fp32 S in out, in-place) --------------

__global__ void scan_init_kernel(const float* __restrict__ S,
                                 const float* __restrict__ a_diag,
                                 float* __restrict__ yinit,
                                 int H, int chunk, int W) {
    int tid = blockIdx.x * blockDim.x + threadIdx.x;
    int h = tid % H, c = tid / H;
    float a = a_diag[h];
    float y = 0.f;
    if (c > 0) {
        int t0 = c * chunk;
        for (int t = t0 - W; t < t0; ++t)
            y = fmaf(a, y, S[(size_t)t * H + h]);
    }
    yinit[(size_t)c * H + h] = y;
}

__global__ void scan_run_kernel(const float* __restrict__ yinit,
                                const float* __restrict__ a_diag,
                                float* __restrict__ out,
                                int H, int chunk) {
    int tid = blockIdx.x * blockDim.x + threadIdx.x;
    int h = tid % H, c = tid / H;
    float a = a_diag[h];
    float y = yinit[(size_t)c * H + h];
    size_t base = (size_t)c * chunk * H + h;
    float s = out[base];
#pragma unroll 4
    for (int t = 0; t < chunk - 1; ++t) {
        float snext = out[base + (size_t)(t + 1) * H];
        y = fmaf(a, y, s);
        out[base + (size_t)t * H] = y;
        s = snext;
    }
    y = fmaf(a, y, s);
    out[base + (size_t)(chunk - 1) * H] = y;
}

// ---------------- fallback (tiny ws): correct but slow ----------------

__global__ void gemm_fallback(const float* __restrict__ X, const float* __restrict__ B,
                              float* __restrict__ C, int M, int N, int K) {
    __shared__ float sA[16][17];
    __shared__ float sB[16][17];
    int tx = threadIdx.x, ty = threadIdx.y;
    int row = blockIdx.y * 16 + ty, col = blockIdx.x * 16 + tx;
    float acc = 0.f;
    for (int k0 = 0; k0 < K; k0 += 16) {
        sA[ty][tx] = (row < M && k0 + tx < K) ? X[(size_t)row * K + k0 + tx] : 0.f;
        sB[ty][tx] = (k0 + ty < K && col < N) ? B[(size_t)(k0 + ty) * N + col] : 0.f;
        __syncthreads();
#pragma unroll
        for (int kk = 0; kk < 16; ++kk) acc += sA[ty][kk] * sB[kk][tx];
        __syncthreads();
    }
    if (row < M && col < N) C[(size_t)row * N + col] = acc;
}

__global__ void scan_serial(float* __restrict__ out, const float* __restrict__ a_diag,
                            int T, int H) {
    int h = blockIdx.x * blockDim.x + threadIdx.x;
    if (h >= H) return;
    float a = a_diag[h], y = 0.f;
    for (int t = 0; t < T; ++t) {
        y = fmaf(a, y, out[(size_t)t * H + h]);
        out[(size_t)t * H + h] = y;
    }
}

// ---------------- launch ----------------

extern "C" void kernel_launch(void* const* d_in, const int* in_sizes, int n_in,
                              void* d_out, int out_size, void* d_ws, size_t ws_size,
                              hipStream_t stream) {
    const float* x = (const float*)d_in[0];   // (T,H)
    const float* a = (const float*)d_in[1];   // (H,)
    const float* b = (const float*)d_in[2];   // (H,H)
    float* out = (float*)d_out;               // (T,H)

    const int H = in_sizes[1];
    const int T = in_sizes[0] / H;
    const int M = T, N = H, K = H;

    const int CHUNK = 16, W = 12;

    size_t xbf_elems = (size_t)M * K;
    size_t bt_elems  = (size_t)N * K;
    size_t MN = (size_t)M * N;
    int nchunks = (T % CHUNK == 0) ? T / CHUNK : 0;

    size_t need_sk  = (xbf_elems + bt_elems + 2 * MN) * 2 + 256;
    size_t need_mid = xbf_elems * 2 + bt_elems * 2 + 256;

    bool shape_ok = (M % 128 == 0) && (N % 128 == 0) && (K % 128 == 0) &&
                    (H % 32 == 0) && nchunks > 0 && ((xbf_elems % 4) == 0) &&
                    (((size_t)nchunks * H) % 256 == 0);
    int gridMf = M / 128;                 // mid-tier (128-tile)
    int gridM  = (M % 256 == 0) ? M / 256 : 0;  // fast path (256-tile)
    int gridN  = N / 128;

    int n4 = (int)(xbf_elems / 4);
    int castBlocks = (n4 + 255) / 256;
    int transBlocks = (H % 32 == 0) ? (H / 32) * (H / 32) : 0;

    int H2 = H / 2;
    size_t nth2 = (size_t)nchunks * H2;

    if (shape_ok && gridM > 0 && (gridM % 8 == 0) && (H % 4 == 0) &&
        (nth2 % 256 == 0) && ws_size >= need_sk) {
        // fast path: 256x128 tiles, split-K=2, bf16 partials, race-free scan
        unsigned short* Xbf = (unsigned short*)d_ws;
        unsigned short* Bt  = Xbf + xbf_elems;
        unsigned short* S0  = Bt + bt_elems;
        unsigned short* S1  = S0 + MN;

        prep_kernel<<<castBlocks + transBlocks, 256, 0, stream>>>(
            x, Xbf, n4, b, Bt, H, castBlocks);

        gemm_sk_bf16out<<<gridM * gridN * 2, 256, 0, stream>>>(
            Xbf, Bt, S0, S1, M, N, K, gridM, gridN);

        scan_splitk_bf16<<<(int)(nth2 / 256), 256, 0, stream>>>(
            S0, S1, a, out, H2, CHUNK);
    } else if (shape_ok && ws_size >= need_mid &&
               ((size_t)nchunks * H * 4 <= xbf_elems * 2)) {
        unsigned short* Xbf = (unsigned short*)d_ws;
        unsigned short* Bt  = Xbf + xbf_elems;
        float* yinit = (float*)d_ws;   // aliases Xbf: dead after gemm reads it

        prep_kernel<<<castBlocks + transBlocks, 256, 0, stream>>>(
            x, Xbf, n4, b, Bt, H, castBlocks);

        gemm_f32out<<<gridMf * gridN, 256, 0, stream>>>(
            Xbf, Bt, out, M, N, K, gridMf);

        int nth = nchunks * H;
        scan_init_kernel<<<nth / 256, 256, 0, stream>>>(out, a, yinit, H, CHUNK, W);
        scan_run_kernel<<<nth / 256, 256, 0, stream>>>(yinit, a, out, H, CHUNK);
    } else {
        dim3 tb(16, 16), tg((N + 15) / 16, (M + 15) / 16);
        gemm_fallback<<<tg, tb, 0, stream>>>(x, b, out, M, N, K);
        scan_serial<<<(H + 255) / 256, 256, 0, stream>>>(out, a, T, H);
    }
}